// Round 1
// baseline (313.394 us; speedup 1.0000x reference)
//
#include <hip/hip_runtime.h>
#include <math.h>

#define TPB 256
#define KC 128
#define WPAD 132            // 128 + 4: spreads expert-row reads across banks
#define TOKS 16             // tokens per block
#define H 2048
#define NE 64

__global__ __launch_bounds__(TPB) void moe_gate_kernel(
    const float* __restrict__ x,   // [T, H]
    const float* __restrict__ w,   // [NE, H]
    float* __restrict__ out,       // [2T idx floats][2T weight floats]
    int woff)                      // = 2*T
{
    __shared__ float  Wl[NE * WPAD];       // 33792 B
    __shared__ double Xd[TOKS * KC];       // 16384 B

    const int tid = threadIdx.x;
    const int e   = tid & 63;              // expert = lane
    const int g   = tid >> 6;              // wave id 0..3
    const int t0  = blockIdx.x * TOKS;

    double acc[4] = {0.0, 0.0, 0.0, 0.0};

    for (int kc = 0; kc < H; kc += KC) {
        // ---- stage W chunk: 64 x 128 floats = 2048 float4, 8 per thread ----
        #pragma unroll
        for (int i = 0; i < 8; ++i) {
            int q   = i * TPB + tid;       // 0..2047 (float4 index)
            int row = q >> 5;              // 32 float4 per row
            int c4  = q & 31;
            const float4 v = *reinterpret_cast<const float4*>(
                &w[(size_t)row * H + kc + c4 * 4]);
            *reinterpret_cast<float4*>(&Wl[row * WPAD + c4 * 4]) = v;
        }
        // ---- stage X chunk: 16 tokens x 128 floats -> double in LDS ----
        #pragma unroll
        for (int i = 0; i < 2; ++i) {
            int q  = i * TPB + tid;        // 0..511 (float4 index)
            int tt = q >> 5;
            int c4 = q & 31;
            const float4 v = *reinterpret_cast<const float4*>(
                &x[(size_t)(t0 + tt) * H + kc + c4 * 4]);
            double* dst = &Xd[tt * KC + c4 * 4];
            dst[0] = (double)v.x; dst[1] = (double)v.y;
            dst[2] = (double)v.z; dst[3] = (double)v.w;
        }
        __syncthreads();

        const float* wr = &Wl[e * WPAD];
        const double* xs0 = &Xd[(g * 4 + 0) * KC];
        const double* xs1 = &Xd[(g * 4 + 1) * KC];
        const double* xs2 = &Xd[(g * 4 + 2) * KC];
        const double* xs3 = &Xd[(g * 4 + 3) * KC];

        #pragma unroll 8
        for (int k = 0; k < KC; k += 4) {
            const float4 wq = *reinterpret_cast<const float4*>(&wr[k]);
            const double wd0 = (double)wq.x, wd1 = (double)wq.y;
            const double wd2 = (double)wq.z, wd3 = (double)wq.w;

            acc[0] = fma(xs0[k + 0], wd0, acc[0]);
            acc[0] = fma(xs0[k + 1], wd1, acc[0]);
            acc[0] = fma(xs0[k + 2], wd2, acc[0]);
            acc[0] = fma(xs0[k + 3], wd3, acc[0]);

            acc[1] = fma(xs1[k + 0], wd0, acc[1]);
            acc[1] = fma(xs1[k + 1], wd1, acc[1]);
            acc[1] = fma(xs1[k + 2], wd2, acc[1]);
            acc[1] = fma(xs1[k + 3], wd3, acc[1]);

            acc[2] = fma(xs2[k + 0], wd0, acc[2]);
            acc[2] = fma(xs2[k + 1], wd1, acc[2]);
            acc[2] = fma(xs2[k + 2], wd2, acc[2]);
            acc[2] = fma(xs2[k + 3], wd3, acc[2]);

            acc[3] = fma(xs3[k + 0], wd0, acc[3]);
            acc[3] = fma(xs3[k + 1], wd1, acc[3]);
            acc[3] = fma(xs3[k + 2], wd2, acc[3]);
            acc[3] = fma(xs3[k + 3], wd3, acc[3]);
        }
        __syncthreads();
    }

    // ---- top-2 over 64 lanes (lane = expert) for each of this wave's 4 tokens
    #pragma unroll
    for (int j = 0; j < 4; ++j) {
        // first max, stable (min index on ties) — matches lax.top_k
        double v  = acc[j];
        int    bi = e;
        #pragma unroll
        for (int off = 32; off > 0; off >>= 1) {
            double ov = __shfl_xor(v, off);
            int    oi = __shfl_xor(bi, off);
            if (ov > v || (ov == v && oi < bi)) { v = ov; bi = oi; }
        }
        const double m1 = v;
        const int    i1 = bi;   // uniform across wave now

        double v2  = (e == i1) ? -1.0e300 : acc[j];
        int    bi2 = e;
        #pragma unroll
        for (int off = 32; off > 0; off >>= 1) {
            double ov = __shfl_xor(v2, off);
            int    oi = __shfl_xor(bi2, off);
            if (ov > v2 || (ov == v2 && oi < bi2)) { v2 = ov; bi2 = oi; }
        }
        const double m2 = v2;
        const int    i2 = bi2;

        if (e == 0) {
            // top-2 normalized softmax: denominator Z cancels
            const double r  = exp(m2 - m1);        // <= 1
            const double s  = 1.0 + r;             // (+1e-20/Z term negligible)
            const float  w1 = (float)(1.0 / s);
            const float  w2 = (float)(r / s);
            const int t = t0 + g * 4 + j;
            out[2 * t + 0]        = (float)i1;
            out[2 * t + 1]        = (float)i2;
            out[woff + 2 * t + 0] = w1;
            out[woff + 2 * t + 1] = w2;
        }
    }
}

extern "C" void kernel_launch(void* const* d_in, const int* in_sizes, int n_in,
                              void* d_out, int out_size, void* d_ws, size_t ws_size,
                              hipStream_t stream) {
    const float* x = (const float*)d_in[0];   // [4*4096, 2048] fp32
    const float* wgt = (const float*)d_in[1]; // [64, 2048] fp32
    float* out = (float*)d_out;               // 65536 floats: [idx | weights]

    const int T = in_sizes[0] / H;            // 16384
    const int woff = out_size / 2;            // 32768

    dim3 grid(T / TOKS);                      // 1024 blocks
    dim3 block(TPB);
    moe_gate_kernel<<<grid, block, 0, stream>>>(x, wgt, out, woff);
}